// Round 8
// baseline (131.897 us; speedup 1.0000x reference)
//
#include <hip/hip_runtime.h>

// BasisFunction2D, round 8 = round-5 champion + VMEM issue reduction.
// Kernel 1 (precompute): per x/z value compute grid index + weight once;
//   zc transposed to [b][j] so the gather reads it as uint4 (2 j per load).
//   Also zeroes out.
// Kernel 2 (main): one block per (o-pair, i) -> 1024 blocks, 512 threads
//   = 1 batch element each. Stage P[:,:,{o0,o1},i,:] as PACKED BF16 o-pairs
//   (38.1 KB LDS -> 4 blocks/CU = 32 waves/CU) using float4 global loads
//   (10 VMEM instrs/thread vs 38 scalar). Gather: 2x ds_read2_b32 per
//   (b, j) serving both outputs, scalar bf16->f32 lerp (R5 math — measured
//   champion), f32 accumulate, atomicAdd over i into out.

#define NG        16
#define NB        17             // NG+1
#define IN_X      32
#define IN_Z      32
#define OUT_DIM   64
#define BATCH     512
#define CELLS     (NB * NB)      // 289
#define LDS_STR   33             // 32 + 1 pad (element units)
#define XSTR      (NB * LDS_STR) // 561
#define QT        (CELLS * 8)    // 2312 quad-tasks per staging
#define NITER     5              // ceil(QT / 512)

__device__ __forceinline__ void grid_coord(float v,
                                           const float* __restrict__ borders,
                                           const float* __restrict__ inv_len,
                                           int& idx, float& w) {
    float e   = expf(-fabsf(v));
    float cdf = (v > 0.f) ? (1.f - 0.5f * e) : (0.5f * e);
    int t = (int)(cdf * 16.f);
    t = t < 0 ? 0 : (t > NG - 1 ? NG - 1 : t);
    idx = t;
    w = (v - borders[t]) * inv_len[t];
}

// pack two floats as bf16 (round-to-nearest-even), lo = a, hi = b
__device__ __forceinline__ unsigned pack_bf16(float a, float b) {
    unsigned ua = __float_as_uint(a);
    unsigned ub = __float_as_uint(b);
    ua += 0x7FFFu + ((ua >> 16) & 1u);
    ub += 0x7FFFu + ((ub >> 16) & 1u);
    return (ua >> 16) | (ub & 0xFFFF0000u);
}
__device__ __forceinline__ float bf_lo(unsigned u) {
    return __uint_as_float(u << 16);
}
__device__ __forceinline__ float bf_hi(unsigned u) {
    return __uint_as_float(u & 0xFFFF0000u);
}

// 32768 threads: gid<16384 -> x table, else z table (transposed [b][j]).
// Also zeroes out[] (32768 elements).
__global__ void precompute_kernel(const float* __restrict__ x,
                                  const float* __restrict__ z,
                                  const float* __restrict__ borders,
                                  const float* __restrict__ inv_len,
                                  float2* __restrict__ xc,   // [32*512]
                                  uint2* __restrict__ zc2,   // [512][32]
                                  float* __restrict__ out) {
    const int gid = blockIdx.x * blockDim.x + threadIdx.x;
    out[gid] = 0.f;
    int idx; float w;
    if (gid < IN_X * BATCH) {
        grid_coord(x[gid], borders, inv_len, idx, w);
        xc[gid] = make_float2(w, __int_as_float(idx * XSTR));
    } else {
        const int g = gid - IN_X * BATCH;   // g = j*512 + b
        const int j = g >> 9;
        const int b = g & (BATCH - 1);
        grid_coord(z[g], borders, inv_len, idx, w);
        zc2[b * IN_Z + j] = make_uint2(__float_as_uint(w),
                                       (unsigned)(idx * LDS_STR));
    }
}

__global__ __launch_bounds__(512, 8)
void bf2d_kernel(const float2* __restrict__ xc,
                 const uint2* __restrict__ zc2,
                 const float* __restrict__ P,
                 float* __restrict__ out) {
    // lds[e] = packed bf16 (P[cell,o0,i,j], P[cell,o1,i,j]), e = cell*33 + j
    __shared__ unsigned lds[CELLS * LDS_STR];   // 9537 dwords = 38148 B

    const int tid = threadIdx.x;                // 512 threads = batch element
    const int o0  = (blockIdx.x & 31) * 2;      // o-pair
    const int i   = blockIdx.x >> 5;

    // ---- stage P[:, :, {o0,o0+1}, i, :] via float4 pairs ----
    // P index: ((cell)*64 + o)*1024 + i*32 + j ; cell stride 65536, o stride 1024
    const float* Pbase = P + (size_t)o0 * 1024 + (size_t)i * 32;
    #pragma unroll
    for (int t = 0; t < NITER; ++t) {
        const int k = tid + t * 512;
        if (k < QT) {
            const int c  = k >> 3;
            const int j4 = (k & 7) << 2;
            const float* g = Pbase + (size_t)c * 65536 + j4;
            const float4 a = *(const float4*)g;            // o0, 4 j's
            const float4 b = *(const float4*)(g + 1024);   // o1, 4 j's
            unsigned* d = &lds[c * LDS_STR + j4];
            d[0] = pack_bf16(a.x, b.x);
            d[1] = pack_bf16(a.y, b.y);
            d[2] = pack_bf16(a.z, b.z);
            d[3] = pack_bf16(a.w, b.w);
        }
    }
    __syncthreads();

    // ---- per-thread: 1 batch element, 2 outputs ----
    const float2 xcv  = xc[i * BATCH + tid];
    const float  wx   = xcv.x;
    const int    xoff = __float_as_int(xcv.y);

    const uint4* zp4 = (const uint4*)(zc2 + (size_t)tid * IN_Z);
    float accx = 0.f, accy = 0.f;
    #pragma unroll 4
    for (int jj = 0; jj < 16; ++jj) {
        const uint4 q = zp4[jj];                 // 2 j's per VMEM load
        {
            const float wz   = __uint_as_float(q.x);
            const int   base = xoff + (int)q.y + 2 * jj;
            const unsigned a0 = lds[base];
            const unsigned a1 = lds[base + LDS_STR];        // ds_read2 pair
            const unsigned b0 = lds[base + XSTR];
            const unsigned b1 = lds[base + XSTR + LDS_STR]; // ds_read2 pair
            const float lox = bf_lo(a0) + wz * (bf_lo(a1) - bf_lo(a0));
            const float loy = bf_hi(a0) + wz * (bf_hi(a1) - bf_hi(a0));
            const float hix = bf_lo(b0) + wz * (bf_lo(b1) - bf_lo(b0));
            const float hiy = bf_hi(b0) + wz * (bf_hi(b1) - bf_hi(b0));
            accx += lox + wx * (hix - lox);
            accy += loy + wx * (hiy - loy);
        }
        {
            const float wz   = __uint_as_float(q.z);
            const int   base = xoff + (int)q.w + 2 * jj + 1;
            const unsigned a0 = lds[base];
            const unsigned a1 = lds[base + LDS_STR];
            const unsigned b0 = lds[base + XSTR];
            const unsigned b1 = lds[base + XSTR + LDS_STR];
            const float lox = bf_lo(a0) + wz * (bf_lo(a1) - bf_lo(a0));
            const float loy = bf_hi(a0) + wz * (bf_hi(a1) - bf_hi(a0));
            const float hix = bf_lo(b0) + wz * (bf_lo(b1) - bf_lo(b0));
            const float hiy = bf_hi(b0) + wz * (bf_hi(b1) - bf_hi(b0));
            accx += lox + wx * (hix - lox);
            accy += loy + wx * (hiy - loy);
        }
    }

    atomicAdd(&out[o0 * BATCH + tid],       accx);
    atomicAdd(&out[(o0 + 1) * BATCH + tid], accy);
}

extern "C" void kernel_launch(void* const* d_in, const int* in_sizes, int n_in,
                              void* d_out, int out_size, void* d_ws, size_t ws_size,
                              hipStream_t stream) {
    const float* x       = (const float*)d_in[0];   // (32, 512)
    const float* z       = (const float*)d_in[1];   // (32, 512)
    const float* P       = (const float*)d_in[2];   // (17,17,64,32,32)
    const float* borders = (const float*)d_in[3];   // (17,)
    const float* inv_len = (const float*)d_in[4];   // (16,)
    float* out = (float*)d_out;                     // (64, 512) = 32768

    float2* xc  = (float2*)d_ws;                    // 16384 float2 = 128 KB
    uint2*  zc2 = (uint2*)(xc + IN_X * BATCH);      // 16384 uint2  = 128 KB

    precompute_kernel<<<dim3(128), dim3(256), 0, stream>>>(
        x, z, borders, inv_len, xc, zc2, out);

    bf2d_kernel<<<dim3((OUT_DIM / 2) * IN_X), dim3(512), 0, stream>>>(
        xc, zc2, P, out);
}